// Round 1
// baseline (154.426 us; speedup 1.0000x reference)
//
#include <hip/hip_runtime.h>
#include <math.h>

typedef float f32x4 __attribute__((ext_vector_type(4)));

// ---------------------------------------------------------------------------
// Kernel 1: build per-axis feature tables in workspace.
// Layout: tab[0 .. 5*W)      = x-axis features, 5 per coord: norm,sign,sin,cos,rtan
//         tab[5*W .. 5*W+5*H) = y-axis features
// Double precision so round(tan(angle)) near the pole matches numpy closely.
// ---------------------------------------------------------------------------
__global__ void pe_table_kernel(const int* __restrict__ hptr,
                                const int* __restrict__ wptr,
                                float* __restrict__ tab) {
    const int H = *hptr;
    const int W = *wptr;
    const int total = W + H;
    for (int i = (int)(blockIdx.x * blockDim.x + threadIdx.x); i < total;
         i += (int)(gridDim.x * blockDim.x)) {
        const bool is_y = (i >= W);
        const int c = is_y ? (i - W) : i;
        const int size = is_y ? H : W;
        double norm = 0.0, angle = 0.0;
        if (size > 1) {
            const double r = (double)c / (double)(size - 1);
            norm = 2.0 * r - 1.0;
            angle = M_PI * r;
        }
        const double d = (double)c - 0.5 * (double)size;
        const float sgn = (d > 0.0) ? 1.0f : ((d < 0.0) ? -1.0f : 0.0f);
        const int base = (is_y ? 5 * W : 0) + 5 * c;
        tab[base + 0] = (float)norm;
        tab[base + 1] = sgn;
        tab[base + 2] = (float)sin(angle);
        tab[base + 3] = (float)cos(angle);
        tab[base + 4] = (float)rint(tan(angle));  // rint = round-half-even, matches jnp.round
    }
}

// Value of flat output element with q = b*S + s (combined index), f in [0,69),
// w,h = pixel coords of s.
__device__ __forceinline__ float pe_value(const float* __restrict__ x,
                                          const float* __restrict__ tab,
                                          unsigned int yoff,
                                          unsigned int q, unsigned int f,
                                          unsigned int w, unsigned int h) {
    if (f == 0u) return x[q];
    const unsigned int g = f - 1u;  // 0..67 feature index
    if (g < 10u) {
        // interleaved x0,y0,x1,y1,... ; feat = g>>1, axis = g&1 (0=x uses w, 1=y uses h)
        const unsigned int feat = g >> 1;
        return (g & 1u) ? tab[yoff + 5u * h + feat] : tab[5u * w + feat];
    }
    if (g < 39u) return (w == g - 10u) ? 1.0f : 0.0f;   // one-hot x, 29 slots
    return (h == g - 39u) ? 1.0f : 0.0f;                // one-hot y, 29 slots
}

// ---------------------------------------------------------------------------
// Kernel 2: flat float4 grid-stride over the output. 16B-aligned coalesced
// nontemporal stores; q = flat/69 gives the x index directly (b*S+s).
// ---------------------------------------------------------------------------
__global__ __launch_bounds__(256) void pe_main_kernel(
    const float* __restrict__ x,
    const int* __restrict__ hptr, const int* __restrict__ wptr,
    const float* __restrict__ tab,
    float* __restrict__ out, unsigned int out_size) {
    const unsigned int W = (unsigned int)*wptr;
    const unsigned int H = (unsigned int)*hptr;
    const unsigned int yoff = 5u * W;
    const unsigned int nF4 = out_size >> 2;
    const unsigned int stride = gridDim.x * blockDim.x;

    for (unsigned int i4 = blockIdx.x * blockDim.x + threadIdx.x; i4 < nF4; i4 += stride) {
        const unsigned int flat = i4 << 2;
        unsigned int q = flat / 69u;          // compile-time magic-mul division
        unsigned int f = flat - q * 69u;
        unsigned int t = q / W;               // q = (b*H + h)*W + w
        unsigned int w = q - t * W;
        unsigned int h = t - (t / H) * H;
        f32x4 v;
#pragma unroll
        for (int e = 0; e < 4; ++e) {
            v[e] = pe_value(x, tab, yoff, q, f, w, h);
            if (++f == 69u) {                 // advance to next output element
                f = 0u;
                ++q;
                if (++w == W) { w = 0u; if (++h == H) h = 0u; }
            }
        }
        __builtin_nontemporal_store(v, (f32x4*)(out + flat));
    }

    // Tail (out_size % 4 != 0) — not hit for the bench shape, kept for safety.
    if (blockIdx.x == 0u && threadIdx.x == 0u) {
        for (unsigned int flat = nF4 << 2; flat < out_size; ++flat) {
            const unsigned int q = flat / 69u;
            const unsigned int f = flat - q * 69u;
            const unsigned int t = q / W;
            const unsigned int w = q - t * W;
            const unsigned int h = t - (t / H) * H;
            out[flat] = pe_value(x, tab, yoff, q, f, w, h);
        }
    }
}

extern "C" void kernel_launch(void* const* d_in, const int* in_sizes, int n_in,
                              void* d_out, int out_size, void* d_ws, size_t ws_size,
                              hipStream_t stream) {
    const float* x = (const float*)d_in[0];
    const int* hptr = (const int*)d_in[1];
    const int* wptr = (const int*)d_in[2];
    float* out = (float*)d_out;
    float* tab = (float*)d_ws;  // needs (W+H)*5*4 bytes = 20 KB for the bench shape

    pe_table_kernel<<<8, 256, 0, stream>>>(hptr, wptr, tab);

    const unsigned int nF4 = ((unsigned int)out_size) >> 2;
    unsigned int blocks = (nF4 + 255u) / 256u;
    if (blocks > 2048u) blocks = 2048u;
    if (blocks == 0u) blocks = 1u;
    pe_main_kernel<<<blocks, 256, 0, stream>>>(x, hptr, wptr, tab, out,
                                               (unsigned int)out_size);
}

// Round 2
// 124.409 us; speedup vs baseline: 1.2413x; 1.2413x over previous
//
#include <hip/hip_runtime.h>
#include <math.h>

typedef float f32x4 __attribute__((ext_vector_type(4)));

#define NF 69u          // output features per row (1 + 68)
#define TILE_ROWS 64u   // rows per block-tile
#define BLOCK 256u

// ---------------------------------------------------------------------------
// Kernel 1: per-axis feature tables in workspace.
// tab[0 .. 5*W)        x-axis: norm,sign,sin,cos,rtan per coord
// tab[5*W .. 5*W+5*H)  y-axis
// Double precision so round(tan) near the pole matches the numpy reference.
// ---------------------------------------------------------------------------
__global__ void pe_table_kernel(const int* __restrict__ hptr,
                                const int* __restrict__ wptr,
                                float* __restrict__ tab) {
    const int H = *hptr;
    const int W = *wptr;
    const int total = W + H;
    for (int i = (int)(blockIdx.x * blockDim.x + threadIdx.x); i < total;
         i += (int)(gridDim.x * blockDim.x)) {
        const bool is_y = (i >= W);
        const int c = is_y ? (i - W) : i;
        const int size = is_y ? H : W;
        double norm = 0.0, angle = 0.0;
        if (size > 1) {
            const double r = (double)c / (double)(size - 1);
            norm = 2.0 * r - 1.0;
            angle = M_PI * r;
        }
        const double d = (double)c - 0.5 * (double)size;
        const float sgn = (d > 0.0) ? 1.0f : ((d < 0.0) ? -1.0f : 0.0f);
        const int base = (is_y ? 5 * W : 0) + 5 * c;
        tab[base + 0] = (float)norm;
        tab[base + 1] = sgn;
        tab[base + 2] = (float)sin(angle);
        tab[base + 3] = (float)cos(angle);
        tab[base + 4] = (float)rint(tan(angle));
    }
}

// ---------------------------------------------------------------------------
// Kernel 2: 64-row tile per block. Compute phase: lane = row within tile,
// wave = feature stride (branch on feature class is wave-uniform; w,h divides
// amortized once per 69 elements). Write phase: linear float4 NT stores.
// ---------------------------------------------------------------------------
__global__ __launch_bounds__(BLOCK) void pe_main_kernel(
    const float* __restrict__ x,
    const int* __restrict__ hptr, const int* __restrict__ wptr,
    const float* __restrict__ tab,
    float* __restrict__ out, unsigned int Q /* = B*H*W rows */) {
    __shared__ float lds[TILE_ROWS * NF];  // 17664 B

    const unsigned int W = (unsigned int)*wptr;
    const unsigned int H = (unsigned int)*hptr;
    const unsigned int yoff = 5u * W;
    const unsigned int ntiles = (Q + TILE_ROWS - 1u) / TILE_ROWS;
    const unsigned int lane = threadIdx.x & 63u;
    const unsigned int wv = threadIdx.x >> 6;

    for (unsigned int T = blockIdx.x; T < ntiles; T += gridDim.x) {
        const unsigned int q = T * TILE_ROWS + lane;
        unsigned int w = 0u, h = 0u;
        float xv = 0.0f;
        const bool valid = q < Q;
        if (valid) {
            const unsigned int t = q / W;   // q = (b*H + h)*W + w
            w = q - t * W;
            h = t - (t / H) * H;
            if (wv == 0u) xv = x[q];        // only wave 0 needs it (f==0)
        }

        // ---- compute phase: wave-uniform feature branches ----
        for (unsigned int f = wv; f < NF; f += 4u) {
            float v;
            if (f == 0u) {
                v = xv;
            } else {
                const unsigned int g = f - 1u;
                if (g < 10u) {
                    const unsigned int feat = g >> 1;
                    v = (g & 1u) ? tab[yoff + 5u * h + feat]
                                 : tab[5u * w + feat];
                } else if (g < 39u) {
                    v = (w == g - 10u) ? 1.0f : 0.0f;
                } else {
                    v = (h == g - 39u) ? 1.0f : 0.0f;
                }
            }
            lds[lane * NF + f] = v;   // stride 69: conflict-free (5 mod 32)
        }
        __syncthreads();

        // ---- write phase: linear float4 NT copy of the tile ----
        const unsigned int rows = (Q - T * TILE_ROWS < TILE_ROWS)
                                      ? (Q - T * TILE_ROWS) : TILE_ROWS;
        const unsigned int nfl = rows * NF;
        const unsigned int n4 = nfl >> 2;
        const size_t obase = (size_t)T * (size_t)(TILE_ROWS * NF);
        const f32x4* lp = (const f32x4*)lds;   // tile base is 16B-aligned
        f32x4* op = (f32x4*)(out + obase);     // 4416*T floats: 16B-aligned
        for (unsigned int j = threadIdx.x; j < n4; j += BLOCK)
            __builtin_nontemporal_store(lp[j], op + j);
        for (unsigned int j = (n4 << 2) + threadIdx.x; j < nfl; j += BLOCK)
            out[obase + j] = lds[j];
        __syncthreads();  // protect LDS before next tile's compute
    }
}

extern "C" void kernel_launch(void* const* d_in, const int* in_sizes, int n_in,
                              void* d_out, int out_size, void* d_ws, size_t ws_size,
                              hipStream_t stream) {
    const float* x = (const float*)d_in[0];
    const int* hptr = (const int*)d_in[1];
    const int* wptr = (const int*)d_in[2];
    float* out = (float*)d_out;
    float* tab = (float*)d_ws;  // (W+H)*5*4 B = 20 KB for the bench shape

    pe_table_kernel<<<8, 256, 0, stream>>>(hptr, wptr, tab);

    const unsigned int Q = (unsigned int)in_sizes[0];  // B*H*W rows
    const unsigned int ntiles = (Q + TILE_ROWS - 1u) / TILE_ROWS;
    unsigned int blocks = ntiles < 2048u ? ntiles : 2048u;
    if (blocks == 0u) blocks = 1u;
    pe_main_kernel<<<blocks, BLOCK, 0, stream>>>(x, hptr, wptr, tab, out, Q);
}

// Round 3
// 112.577 us; speedup vs baseline: 1.3717x; 1.1051x over previous
//
#include <hip/hip_runtime.h>
#include <math.h>

typedef float f32x4 __attribute__((ext_vector_type(4)));

#define NF 69u                         // floats per output row (1 + 68)
#define TILE_ROWS 64u                  // rows per tile
#define TILE_FLOATS (TILE_ROWS * NF)   // 4416
#define BLOCK 256u

// ---------------------------------------------------------------------------
// Kernel 1: per-axis feature tables in workspace.
// tab[0 .. 5*W)        x-axis: norm,sign,sin,cos,rtan per coord
// tab[5*W .. 5*W+5*H)  y-axis
// ---------------------------------------------------------------------------
__global__ void pe_table_kernel(const int* __restrict__ hptr,
                                const int* __restrict__ wptr,
                                float* __restrict__ tab) {
    const int H = *hptr;
    const int W = *wptr;
    const int total = W + H;
    for (int i = (int)(blockIdx.x * blockDim.x + threadIdx.x); i < total;
         i += (int)(gridDim.x * blockDim.x)) {
        const bool is_y = (i >= W);
        const int c = is_y ? (i - W) : i;
        const int size = is_y ? H : W;
        double norm = 0.0, angle = 0.0;
        if (size > 1) {
            const double r = (double)c / (double)(size - 1);
            norm = 2.0 * r - 1.0;
            angle = M_PI * r;
        }
        const double d = (double)c - 0.5 * (double)size;
        const float sgn = (d > 0.0) ? 1.0f : ((d < 0.0) ? -1.0f : 0.0f);
        const int base = (is_y ? 5 * W : 0) + 5 * c;
        tab[base + 0] = (float)norm;
        tab[base + 1] = sgn;
        tab[base + 2] = (float)sin(angle);
        tab[base + 3] = (float)cos(angle);
        tab[base + 4] = (float)rint(tan(angle));
    }
}

// Compute one 64-row tile into an LDS buffer. lane = row-in-tile; the f-loop
// strides by 4 waves so every feature-class branch is wave-uniform.
__device__ __forceinline__ void pe_compute_tile(
    float* __restrict__ buf, unsigned int T, unsigned int Q,
    unsigned int W, unsigned int H, unsigned int yoff,
    const float* __restrict__ x, const float* __restrict__ tab,
    unsigned int lane, unsigned int wv) {
    const unsigned int q = T * TILE_ROWS + lane;
    unsigned int w = 0u, h = 0u;
    float xv = 0.0f;
    if (q < Q) {
        const unsigned int t = q / W;     // q = (b*H + h)*W + w
        w = q - t * W;
        h = t - (t / H) * H;
        xv = x[q];
    }
    for (unsigned int f = wv; f < NF; f += 4u) {
        float v;
        if (f == 0u) {
            v = xv;
        } else {
            const unsigned int g = f - 1u;
            if (g < 10u) {
                const unsigned int feat = g >> 1;
                v = (g & 1u) ? tab[yoff + 5u * h + feat]
                             : tab[5u * w + feat];
            } else if (g < 39u) {
                v = (w == g - 10u) ? 1.0f : 0.0f;
            } else {
                v = (h == g - 39u) ? 1.0f : 0.0f;
            }
        }
        buf[lane * NF + f] = v;   // stride 69 mod 32 = 5: conflict-free
    }
}

// ---------------------------------------------------------------------------
// Kernel 2: double-buffered pipeline, ONE lgkm-only barrier per tile.
// Global NT stores stay in flight across the barrier (no vmcnt drain).
// ---------------------------------------------------------------------------
__global__ __launch_bounds__(BLOCK) void pe_main_kernel(
    const float* __restrict__ x,
    const int* __restrict__ hptr, const int* __restrict__ wptr,
    const float* __restrict__ tab,
    float* __restrict__ out, unsigned int Q /* = B*H*W rows */) {
    __shared__ float lds[2][TILE_FLOATS];  // 2 x 17664 B

    const unsigned int W = (unsigned int)*wptr;
    const unsigned int H = (unsigned int)*hptr;
    const unsigned int yoff = 5u * W;
    const unsigned int ntiles = (Q + TILE_ROWS - 1u) / TILE_ROWS;
    const unsigned int lane = threadIdx.x & 63u;
    const unsigned int wv = threadIdx.x >> 6;
    const unsigned int gstride = gridDim.x;

    unsigned int T = blockIdx.x;
    if (T >= ntiles) return;  // uniform per block

    pe_compute_tile(lds[0], T, Q, W, H, yoff, x, tab, lane, wv);
    unsigned int cur = 0u;

    for (; T < ntiles; T += gstride) {
        // LDS-only barrier: waits ds ops, NOT the in-flight global stores.
        asm volatile("s_waitcnt lgkmcnt(0)\n\ts_barrier" ::: "memory");

        // ---- store tile T from lds[cur]: linear float4 NT copy ----
        const unsigned int rem = Q - T * TILE_ROWS;
        const unsigned int rows = rem < TILE_ROWS ? rem : TILE_ROWS;
        const unsigned int nfl = rows * NF;
        const unsigned int n4 = nfl >> 2;                 // full tile: 1104
        const size_t obase = (size_t)T * (size_t)TILE_FLOATS;
        const f32x4* lp = (const f32x4*)lds[cur];
        f32x4* op = (f32x4*)(out + obase);                // 16B-aligned
        for (unsigned int j = threadIdx.x; j < n4; j += BLOCK)
            __builtin_nontemporal_store(lp[j], op + j);
        for (unsigned int j = (n4 << 2) + threadIdx.x; j < nfl; j += BLOCK)
            __builtin_nontemporal_store(lds[cur][j], out + obase + j);

        // ---- compute tile T+gstride into the other buffer ----
        const unsigned int Tn = T + gstride;
        if (Tn < ntiles)
            pe_compute_tile(lds[cur ^ 1u], Tn, Q, W, H, yoff, x, tab, lane, wv);
        cur ^= 1u;
    }
}

extern "C" void kernel_launch(void* const* d_in, const int* in_sizes, int n_in,
                              void* d_out, int out_size, void* d_ws, size_t ws_size,
                              hipStream_t stream) {
    const float* x = (const float*)d_in[0];
    const int* hptr = (const int*)d_in[1];
    const int* wptr = (const int*)d_in[2];
    float* out = (float*)d_out;
    float* tab = (float*)d_ws;  // (W+H)*5*4 B = 20 KB for the bench shape

    pe_table_kernel<<<8, 256, 0, stream>>>(hptr, wptr, tab);

    const unsigned int Q = (unsigned int)in_sizes[0];  // B*H*W rows
    const unsigned int ntiles = (Q + TILE_ROWS - 1u) / TILE_ROWS;
    unsigned int blocks = ntiles < 2048u ? ntiles : 2048u;
    if (blocks == 0u) blocks = 1u;
    pe_main_kernel<<<blocks, BLOCK, 0, stream>>>(x, hptr, wptr, tab, out, Q);
}